// Round 5
// baseline (640.131 us; speedup 1.0000x reference)
//
#include <hip/hip_runtime.h>

#define N_NODES 50000
#define N_EDGES 800000
#define D_FEAT  64
#define NB      782          // ceil(50000/64) buckets of 64 consecutive nodes
#define HIST_BLOCKS 256

// ---------------------------------------------------------------------------
// Round 5: bucketed (64-node) CSR + LDS accumulation.
//   1. memset counts+galloc (tiny)
//   2. hist:  LDS-privatized bucket histogram, ~200K global no-return atomics
//   3. alloc: atomic segment allocator over 782 buckets (order irrelevant)
//   4. fill:  pos=atomicAdd(cursor[dst>>6]); payload[pos]=(src|dlow<<16, w).
//             Only 782 hot append cursors -> stores cluster near cursors and
//             line-merge in L2 (vs 50K-way scatter: 64B HBM line per 4B store)
//   5. acc:   one WG per bucket. 16KB LDS acc[64 nodes][64 feats].
//             4 waves x 8-edge groups: shfl-broadcast payload, 8 independent
//             coalesced 256B queue-row gathers, 8 no-return ds_add_f32.
//             Coalesced float4 writeout (every node written once).
// ---------------------------------------------------------------------------

__global__ void __launch_bounds__(256)
hist_kernel(const int* __restrict__ dst, int* __restrict__ counts) {
    __shared__ int h[NB];
    for (int b = threadIdx.x; b < NB; b += 256) h[b] = 0;
    __syncthreads();
    const int stride = gridDim.x * blockDim.x;   // 65536
    for (int t = blockIdx.x * blockDim.x + threadIdx.x; t * 4 < N_EDGES; t += stride) {
        int4 d = *reinterpret_cast<const int4*>(dst + t * 4);
        atomicAdd(&h[d.x >> 6], 1);
        atomicAdd(&h[d.y >> 6], 1);
        atomicAdd(&h[d.z >> 6], 1);
        atomicAdd(&h[d.w >> 6], 1);
    }
    __syncthreads();
    for (int b = threadIdx.x; b < NB; b += 256) {
        int c = h[b];
        if (c) atomicAdd(&counts[b], c);
    }
}

__global__ void __launch_bounds__(256)
alloc_kernel(const int* __restrict__ counts, uint2* __restrict__ seg,
             int* __restrict__ cursor, int* __restrict__ galloc) {
    int b = blockIdx.x * blockDim.x + threadIdx.x;
    if (b >= NB) return;
    int c = counts[b];
    int base = atomicAdd(galloc, c);
    seg[b]    = make_uint2((unsigned)base, (unsigned)c);
    cursor[b] = base;
}

__global__ void __launch_bounds__(256)
fill_kernel(const int* __restrict__ src, const int* __restrict__ dst,
            const float* __restrict__ weight, int* __restrict__ cursor,
            uint2* __restrict__ payload) {
    int e = blockIdx.x * blockDim.x + threadIdx.x;
    if (e >= N_EDGES) return;
    int s = src[e], d = dst[e];
    float w = weight[e];
    int pos = atomicAdd(&cursor[d >> 6], 1);
    payload[pos] = make_uint2((unsigned)s | ((unsigned)(d & 63) << 16),
                              __float_as_uint(w));
}

// One WG (4 waves) per bucket; lane = feature column.
__global__ void __launch_bounds__(256)
acc_kernel(const float* __restrict__ queue, const uint2* __restrict__ payload,
           const uint2* __restrict__ seg, float* __restrict__ out) {
    __shared__ float acc[64 * D_FEAT];           // 16 KB: acc[node_low][feat]
    const int tid  = threadIdx.x;
    const int lane = tid & 63;
    const int wv   = tid >> 6;                   // wave 0..3

    float4* av = reinterpret_cast<float4*>(acc);
    for (int i = tid; i < 64 * D_FEAT / 4; i += 256)
        av[i] = make_float4(0.f, 0.f, 0.f, 0.f);
    __syncthreads();

    const uint2 sg = seg[blockIdx.x];
    const uint2* run = payload + sg.x;
    const int cnt = (int)sg.y;
    const int ngroups = cnt >> 3;

    for (int g = wv; g < ngroups; g += 4) {
        // lanes 0..7 hold the group's 8 payload entries; broadcast via shfl
        uint2 mine = run[g * 8 + (lane & 7)];
        float qv[8], wv8[8];
        int   dl[8];
#pragma unroll
        for (int j = 0; j < 8; ++j) {
            unsigned ex = __shfl((int)mine.x, j);
            unsigned ey = __shfl((int)mine.y, j);
            dl[j]  = (int)((ex >> 16) & 63);
            wv8[j] = __uint_as_float(ey);
            qv[j]  = queue[(size_t)(ex & 0xffffu) * D_FEAT + lane];  // coalesced 256B
        }
#pragma unroll
        for (int j = 0; j < 8; ++j)
            atomicAdd(&acc[dl[j] * D_FEAT + lane], qv[j] * wv8[j]);  // ds_add_f32
    }
    if (wv == 0) {  // tail (< 8 edges)
        for (int i = ngroups * 8; i < cnt; ++i) {
            uint2 e = run[i];
            float q = queue[(size_t)(e.x & 0xffffu) * D_FEAT + lane];
            atomicAdd(&acc[((e.x >> 16) & 63) * D_FEAT + lane],
                      q * __uint_as_float(e.y));
        }
    }
    __syncthreads();

    // write 64 nodes x 64 feats, coalesced float4, clipped at N_NODES
    const int nodebase = blockIdx.x * 64;
    float4* ov = reinterpret_cast<float4*>(out + (size_t)nodebase * D_FEAT);
#pragma unroll
    for (int k = 0; k < 4; ++k) {
        int idx  = tid + k * 256;                // float4 index within bucket
        int node = nodebase + (idx >> 4);
        if (node < N_NODES) ov[idx] = av[idx];
    }
}

// --- Fallback (round-1 scatter) if ws_size is ever too small ---------------
__global__ void __launch_bounds__(256)
scatter_add_kernel(const float* __restrict__ queue,
                   const float* __restrict__ weight,
                   const int* __restrict__ src,
                   const int* __restrict__ dst,
                   float* __restrict__ out) {
    long long tid = (long long)blockIdx.x * blockDim.x + threadIdx.x;
    int e = (int)(tid >> 4);
    int c = ((int)tid & 15) << 2;
    if (e >= N_EDGES) return;
    int s = src[e], d = dst[e];
    float w = weight[e];
    const float4 q = *reinterpret_cast<const float4*>(queue + (size_t)s * D_FEAT + c);
    float* o = out + (size_t)d * D_FEAT + c;
    atomicAdd(o + 0, q.x * w);
    atomicAdd(o + 1, q.y * w);
    atomicAdd(o + 2, q.z * w);
    atomicAdd(o + 3, q.w * w);
}

extern "C" void kernel_launch(void* const* d_in, const int* in_sizes, int n_in,
                              void* d_out, int out_size, void* d_ws, size_t ws_size,
                              hipStream_t stream) {
    const float* queue  = (const float*)d_in[0];
    const float* weight = (const float*)d_in[1];
    const int*   src    = (const int*)d_in[2];
    const int*   dst    = (const int*)d_in[3];
    float* out = (float*)d_out;

    // Workspace layout (payload 8B-aligned at base):
    //   payload: N_EDGES uint2   (6.4 MB)
    //   seg:     NB uint2
    //   counts:  NB int   \ zeroed together (galloc adjacent)
    //   galloc:  1 int    /
    //   cursor:  NB int
    const size_t pay_bytes = (size_t)N_EDGES * sizeof(uint2);
    const size_t need = pay_bytes + (size_t)NB * sizeof(uint2)
                      + (size_t)(2 * NB + 1) * sizeof(int);

    if (ws_size < need) {  // safety fallback: round-1 scatter path
        hipMemsetAsync(out, 0, (size_t)out_size * sizeof(float), stream);
        const long long total = (long long)N_EDGES * 16;
        scatter_add_kernel<<<(int)((total + 255) / 256), 256, 0, stream>>>(
            queue, weight, src, dst, out);
        return;
    }

    char* ws = (char*)d_ws;
    uint2* payload = (uint2*)ws;
    uint2* seg     = (uint2*)(ws + pay_bytes);
    int* counts    = (int*)(seg + NB);
    int* galloc    = counts + NB;
    int* cursor    = galloc + 1;

    hipMemsetAsync(counts, 0, (size_t)(NB + 1) * sizeof(int), stream);

    hist_kernel <<<HIST_BLOCKS, 256, 0, stream>>>(dst, counts);
    alloc_kernel<<<(NB + 255) / 256, 256, 0, stream>>>(counts, seg, cursor, galloc);
    fill_kernel <<<(N_EDGES + 255) / 256, 256, 0, stream>>>(src, dst, weight,
                                                            cursor, payload);
    acc_kernel  <<<NB, 256, 0, stream>>>(queue, payload, seg, out);
}

// Round 6
// 315.079 us; speedup vs baseline: 2.0317x; 2.0317x over previous
//
#include <hip/hip_runtime.h>
#include <hip/hip_fp16.h>

#define N_NODES 50000
#define N_EDGES 800000
#define D_FEAT  64
#define NB      782                       // ceil(50000/64) buckets of 64 nodes
#define CSR_CAP (N_EDGES + 4 * N_NODES)   // padded 4B entries (4 MB)

// ---------------------------------------------------------------------------
// Round 6: two-level counting sort -> exact padded per-node CSR -> float4 pull
//   A. hist:  LDS-privatized 782-bucket histogram (~200K global atomics)
//   B. fill:  append (src|dlow<<16, w_fp32) 8B payloads to 782 bucket runs.
//             Appends cluster at the cursor -> L2 line-merge (vs R4's 50K-way
//             scatter where every 4B store cost a 64B line writeback).
//   C. sort:  one WG per bucket: LDS 64-ctr hist + wave scan (pad to x4) ->
//             scatter into bucket's CONTIGUOUS csr region (line-merged),
//             entries packed 4B: src<<16 | fp16(w). Writes seg[node].
//   D. pull:  one wave per node. 16 lanes x float4 per queue row -> 4 edges
//             per load instr, 8 edges in flight; shfl_xor slot reduction;
//             lanes 0-15 store one float4 each (256B/node, coalesced).
// ---------------------------------------------------------------------------

__device__ __forceinline__ unsigned pack_entry(unsigned s, float w) {
    return (s << 16) | (unsigned)__half_as_ushort(__float2half(w));
}
__device__ __forceinline__ float entry_w(unsigned e) {
    return __half2float(__ushort_as_half((unsigned short)(e & 0xffffu)));
}

// A ------------------------------------------------------------------------
__global__ void __launch_bounds__(256)
hist_kernel(const int* __restrict__ dst, int* __restrict__ counts) {
    __shared__ int h[NB];
    for (int b = threadIdx.x; b < NB; b += 256) h[b] = 0;
    __syncthreads();
    const int stride = gridDim.x * blockDim.x;
    for (int t = blockIdx.x * blockDim.x + threadIdx.x; t * 4 < N_EDGES; t += stride) {
        int4 d = *reinterpret_cast<const int4*>(dst + t * 4);
        atomicAdd(&h[d.x >> 6], 1);
        atomicAdd(&h[d.y >> 6], 1);
        atomicAdd(&h[d.z >> 6], 1);
        atomicAdd(&h[d.w >> 6], 1);
    }
    __syncthreads();
    for (int b = threadIdx.x; b < NB; b += 256) {
        int c = h[b];
        if (c) atomicAdd(&counts[b], c);
    }
}

__global__ void __launch_bounds__(256)
alloc_kernel(const int* __restrict__ counts, uint2* __restrict__ segb,
             int* __restrict__ cursor, int* __restrict__ galloc) {
    int b = blockIdx.x * blockDim.x + threadIdx.x;
    if (b >= NB) return;
    int c = counts[b];
    int base = atomicAdd(galloc, c);
    segb[b]   = make_uint2((unsigned)base, (unsigned)c);
    cursor[b] = base;
}

// B ------------------------------------------------------------------------
__global__ void __launch_bounds__(256)
fill_kernel(const int* __restrict__ src, const int* __restrict__ dst,
            const float* __restrict__ weight, int* __restrict__ cursor,
            uint2* __restrict__ payload) {
    int e = blockIdx.x * blockDim.x + threadIdx.x;
    if (e >= N_EDGES) return;
    int s = src[e], d = dst[e];
    float w = weight[e];
    int pos = atomicAdd(&cursor[d >> 6], 1);
    payload[pos] = make_uint2((unsigned)s | ((unsigned)(d & 63) << 16),
                              __float_as_uint(w));
}

// C ------------------------------------------------------------------------
__global__ void __launch_bounds__(256)
sort_kernel(const uint2* __restrict__ payload, const uint2* __restrict__ segb,
            unsigned* __restrict__ csr, uint2* __restrict__ seg,
            int* __restrict__ gcsr) {
    __shared__ int cnt[64], beg[64], cur[64];
    const int tid = threadIdx.x;
    if (tid < 64) cnt[tid] = 0;
    __syncthreads();

    const uint2 sb = segb[blockIdx.x];
    const uint2* run = payload + sb.x;
    const int cb = (int)sb.y;

    for (int i = tid; i < cb; i += 256)
        atomicAdd(&cnt[(run[i].x >> 16) & 63], 1);
    __syncthreads();

    if (tid < 64) {                       // wave 0: scan + allocate + pads
        int c  = cnt[tid];
        int c4 = (c + 3) & ~3;            // pad each node segment to x4
        int incl = c4;
        for (int off = 1; off < 64; off <<= 1) {
            int v = __shfl_up(incl, off, 64);
            if (tid >= off) incl += v;
        }
        int excl  = incl - c4;
        int total = __shfl(incl, 63, 64);
        int gbase = 0;
        if (tid == 63) gbase = atomicAdd(gcsr, total);
        gbase = __shfl(gbase, 63, 64);
        int b = gbase + excl;
        beg[tid] = b;
        cur[tid] = 0;
        int node = blockIdx.x * 64 + tid;
        if (node < N_NODES) seg[node] = make_uint2((unsigned)b, (unsigned)c4);
        for (int k = c; k < c4; ++k) csr[b + k] = 0u;  // src=0, w=fp16(0)
    }
    __syncthreads();

    for (int i = tid; i < cb; i += 256) {
        uint2 u = run[i];
        int d = (u.x >> 16) & 63;
        int pos = beg[d] + atomicAdd(&cur[d], 1);
        csr[pos] = pack_entry(u.x & 0xffffu, __uint_as_float(u.y));
    }
}

// D ------------------------------------------------------------------------
// One wave per node; 4 nodes per 256-thread block.
// lane = 16*slot + f4idx: slot in [0,4) handles edges i+slot / i+4+slot,
// f4idx picks the float4 column of the 256B queue row.
__global__ void __launch_bounds__(256)
pull_kernel(const float* __restrict__ queue, const unsigned* __restrict__ csr,
            const uint2* __restrict__ seg, float* __restrict__ out) {
    const int node  = blockIdx.x * 4 + (threadIdx.x >> 6);
    const int lane  = threadIdx.x & 63;
    const int slot  = lane >> 4;
    const int f4idx = lane & 15;
    if (node >= N_NODES) return;

    const uint2 sg = seg[node];
    const unsigned* p = csr + sg.x;
    const int n4 = (int)sg.y;

    float4 acc = make_float4(0.f, 0.f, 0.f, 0.f);
    int i = 0;
    for (; i + 8 <= n4; i += 8) {          // 8 edges in flight
        unsigned ea = p[i + slot];
        unsigned eb = p[i + 4 + slot];
        const float4 qa = *reinterpret_cast<const float4*>(
            queue + (size_t)(ea >> 16) * D_FEAT + f4idx * 4);
        const float4 qb = *reinterpret_cast<const float4*>(
            queue + (size_t)(eb >> 16) * D_FEAT + f4idx * 4);
        float wa = entry_w(ea), wb = entry_w(eb);
        acc.x = fmaf(qa.x, wa, acc.x); acc.y = fmaf(qa.y, wa, acc.y);
        acc.z = fmaf(qa.z, wa, acc.z); acc.w = fmaf(qa.w, wa, acc.w);
        acc.x = fmaf(qb.x, wb, acc.x); acc.y = fmaf(qb.y, wb, acc.y);
        acc.z = fmaf(qb.z, wb, acc.z); acc.w = fmaf(qb.w, wb, acc.w);
    }
    if (i < n4) {                          // one remaining group of 4
        unsigned ea = p[i + slot];
        const float4 qa = *reinterpret_cast<const float4*>(
            queue + (size_t)(ea >> 16) * D_FEAT + f4idx * 4);
        float wa = entry_w(ea);
        acc.x = fmaf(qa.x, wa, acc.x); acc.y = fmaf(qa.y, wa, acc.y);
        acc.z = fmaf(qa.z, wa, acc.z); acc.w = fmaf(qa.w, wa, acc.w);
    }

    // reduce across the 4 slots (lanes ^16, ^32)
#pragma unroll
    for (int m = 16; m <= 32; m <<= 1) {
        acc.x += __shfl_xor(acc.x, m, 64);
        acc.y += __shfl_xor(acc.y, m, 64);
        acc.z += __shfl_xor(acc.z, m, 64);
        acc.w += __shfl_xor(acc.w, m, 64);
    }
    if (slot == 0)                          // 16 lanes x float4 = 256B/node
        *reinterpret_cast<float4*>(out + (size_t)node * D_FEAT + f4idx * 4) = acc;
}

// --- Fallback (round-1 scatter) if ws_size is ever too small ---------------
__global__ void __launch_bounds__(256)
scatter_add_kernel(const float* __restrict__ queue,
                   const float* __restrict__ weight,
                   const int* __restrict__ src,
                   const int* __restrict__ dst,
                   float* __restrict__ out) {
    long long tid = (long long)blockIdx.x * blockDim.x + threadIdx.x;
    int e = (int)(tid >> 4);
    int c = ((int)tid & 15) << 2;
    if (e >= N_EDGES) return;
    int s = src[e], d = dst[e];
    float w = weight[e];
    const float4 q = *reinterpret_cast<const float4*>(queue + (size_t)s * D_FEAT + c);
    float* o = out + (size_t)d * D_FEAT + c;
    atomicAdd(o + 0, q.x * w);
    atomicAdd(o + 1, q.y * w);
    atomicAdd(o + 2, q.z * w);
    atomicAdd(o + 3, q.w * w);
}

extern "C" void kernel_launch(void* const* d_in, const int* in_sizes, int n_in,
                              void* d_out, int out_size, void* d_ws, size_t ws_size,
                              hipStream_t stream) {
    const float* queue  = (const float*)d_in[0];
    const float* weight = (const float*)d_in[1];
    const int*   src    = (const int*)d_in[2];
    const int*   dst    = (const int*)d_in[3];
    float* out = (float*)d_out;

    // Workspace layout:
    //   payload: N_EDGES uint2       (6.4 MB)
    //   csr:     CSR_CAP unsigned    (4.0 MB)
    //   seg:     N_NODES uint2       (per-node beg,c4)
    //   segb:    NB uint2
    //   counts:  NB int  \
    //   galloc:  1 int    > zeroed together
    //   gcsr:    1 int   /
    //   cursor:  NB int
    const size_t pay_bytes = (size_t)N_EDGES * sizeof(uint2);
    const size_t csr_bytes = (size_t)CSR_CAP * sizeof(unsigned);
    const size_t need = pay_bytes + csr_bytes
                      + (size_t)(N_NODES + NB) * sizeof(uint2)
                      + (size_t)(2 * NB + 2) * sizeof(int);

    if (ws_size < need) {  // safety fallback: round-1 scatter path
        hipMemsetAsync(out, 0, (size_t)out_size * sizeof(float), stream);
        const long long total = (long long)N_EDGES * 16;
        scatter_add_kernel<<<(int)((total + 255) / 256), 256, 0, stream>>>(
            queue, weight, src, dst, out);
        return;
    }

    char* ws = (char*)d_ws;
    uint2* payload = (uint2*)ws;
    unsigned* csr  = (unsigned*)(ws + pay_bytes);
    uint2* seg     = (uint2*)(ws + pay_bytes + csr_bytes);
    uint2* segb    = seg + N_NODES;
    int* counts    = (int*)(segb + NB);
    int* galloc    = counts + NB;
    int* gcsr      = galloc + 1;
    int* cursor    = gcsr + 1;

    hipMemsetAsync(counts, 0, (size_t)(NB + 2) * sizeof(int), stream);

    hist_kernel <<<256, 256, 0, stream>>>(dst, counts);
    alloc_kernel<<<(NB + 255) / 256, 256, 0, stream>>>(counts, segb, cursor, galloc);
    fill_kernel <<<(N_EDGES + 255) / 256, 256, 0, stream>>>(src, dst, weight,
                                                            cursor, payload);
    sort_kernel <<<NB, 256, 0, stream>>>(payload, segb, csr, seg, gcsr);
    pull_kernel <<<(N_NODES + 3) / 4, 256, 0, stream>>>(queue, csr, seg, out);
}